// Round 8
// baseline (370.051 us; speedup 1.0000x reference)
//
#include <hip/hip_runtime.h>
#include <hip/hip_fp16.h>
#include <math.h>

// ---------------------------------------------------------------------------
// SolventGCN round 8: fuse aggregate -> next-layer MFMA GEMM (LDS X-tile, no
// intermediate activation buffer for layers 0->1 and 1->2).
//   zero -> p1_partition -> p2_scanbuckets -> p3_build -> gemmBoth0(MFMA)
//   -> aggGemmBoth(L0 agg + L1 gemm) -> aggGemmBoth(L1 agg + L2 gemm)
//   -> aggBoth(L2 agg) -> poolDense.   9 launches.
// Agg gather pattern is unchanged (it sits at the compulsory L2-miss floor,
// FETCH~112MB); fusion removes the 18.75MB buf write + re-read per layer.
// ---------------------------------------------------------------------------

static inline int cdiv(int a, int b) { return (a + b - 1) / b; }

#define BUCKET_CAP 8192
#define P1_CHUNK   4096

typedef _Float16 v8h __attribute__((ext_vector_type(8)));
typedef float    v4f __attribute__((ext_vector_type(4)));

__global__ void zero_int(int* __restrict__ p, int n) {
    int i = blockIdx.x * blockDim.x + threadIdx.x;
    if (i < n) p[i] = 0;
}

// ---- pass 1: partition edges into buckets (packed) ----
__global__ __launch_bounds__(256) void p1_partition(const int* __restrict__ c_edge, int Ec,
                                                    const int* __restrict__ s_edge, int Es,
                                                    int Nc_pad, int Etot, int nbuck,
                                                    int* __restrict__ bucket_fill,
                                                    unsigned* __restrict__ pk) {
    __shared__ unsigned       wbuf[P1_CHUNK];
    __shared__ unsigned short bbuf[P1_CHUNK];
    __shared__ int            hist[512];
    int e0 = blockIdx.x * P1_CHUNK;
    int n  = Etot - e0;
    if (n > P1_CHUNK) n = P1_CHUNK;
    for (int i = threadIdx.x; i < nbuck; i += 256) hist[i] = 0;
    __syncthreads();
    for (int i = threadIdx.x; i < n; i += 256) {
        int e = e0 + i, src, g;
        if (e < Ec) { src = c_edge[e]; g = c_edge[Ec + e]; }
        else        { int e2 = e - Ec; src = s_edge[e2]; g = Nc_pad + s_edge[Es + e2]; }
        int b   = g >> 9;
        wbuf[i] = ((unsigned)(g & 511) << 17) | (unsigned)src;
        bbuf[i] = (unsigned short)b;
        atomicAdd(&hist[b], 1);
    }
    __syncthreads();
    for (int i = threadIdx.x; i < nbuck; i += 256) {
        int h = hist[i];
        hist[i] = h ? atomicAdd(&bucket_fill[i], h) : 0;
    }
    __syncthreads();
    for (int i = threadIdx.x; i < n; i += 256) {
        int b    = bbuf[i];
        int slot = atomicAdd(&hist[b], 1);
        if (slot < BUCKET_CAP) pk[(size_t)b * BUCKET_CAP + slot] = wbuf[i];
    }
}

// ---- pass 2: exclusive scan of bucket fills ----
__global__ __launch_bounds__(512) void p2_scanbuckets(const int* __restrict__ fill, int nbuck,
                                                      int* __restrict__ basearr,
                                                      int* __restrict__ off_all, int Ntot_pad, int Etot) {
    __shared__ int sh[512];
    int v = (threadIdx.x < nbuck) ? fill[threadIdx.x] : 0;
    sh[threadIdx.x] = v;
    __syncthreads();
    for (int ofs = 1; ofs < 512; ofs <<= 1) {
        int t = (threadIdx.x >= ofs) ? sh[threadIdx.x - ofs] : 0;
        __syncthreads();
        sh[threadIdx.x] += t;
        __syncthreads();
    }
    if (threadIdx.x < nbuck) basearr[threadIdx.x] = sh[threadIdx.x] - v;
    if (threadIdx.x == 0) off_all[Ntot_pad] = Etot;
}

// ---- pass 3: per-bucket CSR build (all per-edge atomics in LDS) ----
__global__ __launch_bounds__(512) void p3_build(const unsigned* __restrict__ pk,
                                                const int* __restrict__ fillarr,
                                                const int* __restrict__ basearr,
                                                int* __restrict__ off_all,
                                                float* __restrict__ dinv,
                                                int* __restrict__ csr) {
    __shared__ int sh[512];
    int b    = blockIdx.x;
    int fill = fillarr[b];
    if (fill > BUCKET_CAP) fill = BUCKET_CAP;
    int base = basearr[b];
    const unsigned* reg = pk + (size_t)b * BUCKET_CAP;
    sh[threadIdx.x] = 0;
    __syncthreads();
    for (int i = threadIdx.x; i < fill; i += 512) atomicAdd(&sh[reg[i] >> 17], 1);
    __syncthreads();
    int cnt = sh[threadIdx.x];
    for (int ofs = 1; ofs < 512; ofs <<= 1) {   // inclusive scan
        int t = (threadIdx.x >= ofs) ? sh[threadIdx.x - ofs] : 0;
        __syncthreads();
        sh[threadIdx.x] += t;
        __syncthreads();
    }
    int excl = sh[threadIdx.x] - cnt;
    int node = b * 512 + threadIdx.x;           // padded-global id
    off_all[node] = base + excl;
    dinv[node]    = rsqrtf((float)(cnt + 1));   // +1 self-loop
    __syncthreads();
    sh[threadIdx.x] = excl;   // cursor for CSR scatter
    __syncthreads();
    for (int i = threadIdx.x; i < fill; i += 512) {
        unsigned w    = reg[i];
        int      slot = atomicAdd(&sh[w >> 17], 1);
        csr[base + slot] = (int)(w & 0x1FFFFu);
    }
}

__device__ __forceinline__ float4 load4h(const float2* __restrict__ base, size_t idx) {
    float2 r = base[idx];
    union { float2 f2; __half2 h2[2]; } u;
    u.f2 = r;
    float2 a = __half22float2(u.h2[0]);
    float2 b = __half22float2(u.h2[1]);
    return make_float4(a.x, a.y, b.x, b.y);
}

// edge-gather accumulate for one node's float4 lane-slice
__device__ __forceinline__ void gather_acc(const float2* __restrict__ H4, int L, int fq,
                                           const int* __restrict__ csr, int j0, int j1,
                                           float4& acc) {
    int j = j0;
    for (; j + 8 <= j1; j += 8) {
        int s0 = csr[j],     s1 = csr[j + 1], s2 = csr[j + 2], s3 = csr[j + 3];
        int s4 = csr[j + 4], s5 = csr[j + 5], s6 = csr[j + 6], s7 = csr[j + 7];
        float4 a0 = load4h(H4, (size_t)s0 * L + fq);
        float4 a1 = load4h(H4, (size_t)s1 * L + fq);
        float4 a2 = load4h(H4, (size_t)s2 * L + fq);
        float4 a3 = load4h(H4, (size_t)s3 * L + fq);
        float4 a4 = load4h(H4, (size_t)s4 * L + fq);
        float4 a5 = load4h(H4, (size_t)s5 * L + fq);
        float4 a6 = load4h(H4, (size_t)s6 * L + fq);
        float4 a7 = load4h(H4, (size_t)s7 * L + fq);
        acc.x += (a0.x + a1.x + a2.x + a3.x) + (a4.x + a5.x + a6.x + a7.x);
        acc.y += (a0.y + a1.y + a2.y + a3.y) + (a4.y + a5.y + a6.y + a7.y);
        acc.z += (a0.z + a1.z + a2.z + a3.z) + (a4.z + a5.z + a6.z + a7.z);
        acc.w += (a0.w + a1.w + a2.w + a3.w) + (a4.w + a5.w + a6.w + a7.w);
    }
    for (; j + 4 <= j1; j += 4) {
        int s0 = csr[j], s1 = csr[j + 1], s2 = csr[j + 2], s3 = csr[j + 3];
        float4 a0 = load4h(H4, (size_t)s0 * L + fq);
        float4 a1 = load4h(H4, (size_t)s1 * L + fq);
        float4 a2 = load4h(H4, (size_t)s2 * L + fq);
        float4 a3 = load4h(H4, (size_t)s3 * L + fq);
        acc.x += a0.x + a1.x + a2.x + a3.x;
        acc.y += a0.y + a1.y + a2.y + a3.y;
        acc.z += a0.z + a1.z + a2.z + a3.z;
        acc.w += a0.w + a1.w + a2.w + a3.w;
    }
    for (; j < j1; ++j) {
        float4 a = load4h(H4, (size_t)csr[j] * L + fq);
        acc.x += a.x; acc.y += a.y; acc.z += a.z; acc.w += a.w;
    }
}

// ---- MFMA GEMM body: H[N][M] = fp16((X @ W) * dinv[row]) (standalone, layer 0) ----
template <int K, int M, typename TIN>
__device__ void gemm_mfma(int bid, const TIN* __restrict__ X, const float* __restrict__ W,
                          const float* __restrict__ dinv, __half* __restrict__ H, int N,
                          char* smem_) {
    constexpr int RB = 64, KP = K + 8, NT = M / 16, KS = K / 32;
    _Float16* Xh = (_Float16*)smem_;           // [RB][KP]
    _Float16* Wz = Xh + RB * KP;               // [NT*KS*64][8]
    const int t    = threadIdx.x;
    const int row0 = bid * RB;

    constexpr int WENT = NT * KS * 64;
    for (int idx = t; idx < WENT; idx += 256) {
        int lane = idx & 63, rest = idx >> 6;
        int ks = rest % KS, ntl = rest / KS;
        int kbase = ks * 32 + (lane >> 4) * 8;
        int col   = ntl * 16 + (lane & 15);
        union { float4 f4; _Float16 h[8]; } u;
#pragma unroll
        for (int j = 0; j < 8; ++j) u.h[j] = (_Float16)W[(kbase + j) * M + col];
        *(float4*)(Wz + idx * 8) = u.f4;
    }
    if constexpr (sizeof(TIN) == 4) {
        constexpr int NI = RB * K / 4;
        for (int idx = t; idx < NI; idx += 256) {
            int row = idx / (K / 4), k4 = idx % (K / 4);
            int gr = row0 + row;
            float4 v = make_float4(0.f, 0.f, 0.f, 0.f);
            if (gr < N) v = *(const float4*)((const float*)X + (size_t)gr * K + k4 * 4);
            union { float2 f2; _Float16 h[4]; } u;
            u.h[0] = (_Float16)v.x; u.h[1] = (_Float16)v.y;
            u.h[2] = (_Float16)v.z; u.h[3] = (_Float16)v.w;
            *(float2*)(Xh + row * KP + k4 * 4) = u.f2;
        }
    } else {
        constexpr int NI = RB * K / 8;
        for (int idx = t; idx < NI; idx += 256) {
            int row = idx / (K / 8), k8 = idx % (K / 8);
            int gr = row0 + row;
            float4 v = make_float4(0.f, 0.f, 0.f, 0.f);
            if (gr < N) v = *(const float4*)((const __half*)X + (size_t)gr * K + k8 * 8);
            *(float4*)(Xh + row * KP + k8 * 8) = v;
        }
    }
    __syncthreads();

    const int wave = t >> 6, lane = t & 63;
    const int quad = lane >> 4, nl = lane & 15;
    const int rowA = wave * 16 + nl;

    v4f acc[NT];
#pragma unroll
    for (int i = 0; i < NT; ++i) acc[i] = (v4f){0.f, 0.f, 0.f, 0.f};
#pragma unroll
    for (int ks = 0; ks < KS; ++ks) {
        v8h a = *(const v8h*)(Xh + rowA * KP + ks * 32 + quad * 8);
#pragma unroll
        for (int ntl = 0; ntl < NT; ++ntl) {
            v8h b = *(const v8h*)(Wz + ((ntl * KS + ks) * 64 + lane) * 8);
            acc[ntl] = __builtin_amdgcn_mfma_f32_16x16x32_f16(a, b, acc[ntl], 0, 0, 0);
        }
    }
#pragma unroll
    for (int r = 0; r < 4; ++r) {
        int gr = row0 + wave * 16 + quad * 4 + r;
        if (gr < N) {
            float dv = dinv[gr];
#pragma unroll
            for (int ntl = 0; ntl < NT; ++ntl)
                H[(size_t)gr * M + ntl * 16 + nl] = __float2half(acc[ntl][r] * dv);
        }
    }
}

// ---- fused aggregate -> next-layer GEMM body (square M x M layer) ----
// Block = 64 dst nodes. Agg writes relu'd rows to LDS X-tile; MFMA phase
// computes Hout = fp16((X @ Wnext) * dinv[row]).
template <int M>
__device__ void aggGemm_body(int bid, const __half* __restrict__ Hin,
                             const int* __restrict__ off_g, const int* __restrict__ csr,
                             const float* __restrict__ dinv_g, const float* __restrict__ bvec,
                             const float* __restrict__ Wnext, __half* __restrict__ Hout,
                             int Nloc, char* smem_) {
    constexpr int KP = M + 8, NT = M / 16, KS = M / 32;
    constexpr int L = M / 4, NPW = 64 / L, ROUNDS = 64 / (4 * NPW);
    _Float16* Xh = (_Float16*)smem_;   // [64][KP]
    _Float16* Wz = Xh + 64 * KP;       // [NT*KS*64][8]
    const int t = threadIdx.x;
    const int row0 = bid * 64;
    const int lane = t & 63, wave = t >> 6;

    // stage W fragments
    constexpr int WENT = NT * KS * 64;
    for (int idx = t; idx < WENT; idx += 256) {
        int ln = idx & 63, rest = idx >> 6;
        int ks = rest % KS, ntl = rest / KS;
        int kbase = ks * 32 + (ln >> 4) * 8;
        int col   = ntl * 16 + (ln & 15);
        union { float4 f4; _Float16 h[8]; } u;
#pragma unroll
        for (int j = 0; j < 8; ++j) u.h[j] = (_Float16)Wnext[(kbase + j) * M + col];
        *(float4*)(Wz + idx * 8) = u.f4;
    }

    // agg phase: each round, wave covers NPW nodes
    const int fq = lane & (L - 1), sub = lane / L;
    const float2* H4 = (const float2*)Hin;
#pragma unroll
    for (int r = 0; r < ROUNDS; ++r) {
        int local = r * (4 * NPW) + wave * NPW + sub;
        int node  = row0 + local;
        float4 acc = make_float4(0.f, 0.f, 0.f, 0.f);
        if (node < Nloc) {
            int j0 = off_g[node], j1 = off_g[node + 1];
            acc = load4h(H4, (size_t)node * L + fq);   // self-loop
            gather_acc(H4, L, fq, csr, j0, j1, acc);
            float  dv = dinv_g[node];
            float4 bb = ((const float4*)bvec)[fq];
            acc.x = fmaxf(dv * acc.x + bb.x, 0.f);
            acc.y = fmaxf(dv * acc.y + bb.y, 0.f);
            acc.z = fmaxf(dv * acc.z + bb.z, 0.f);
            acc.w = fmaxf(dv * acc.w + bb.w, 0.f);
        }
        union { float2 f2; __half2 hh[2]; } o;
        o.hh[0] = __floats2half2_rn(acc.x, acc.y);
        o.hh[1] = __floats2half2_rn(acc.z, acc.w);
        *(float2*)(Xh + local * KP + 4 * fq) = o.f2;
    }
    __syncthreads();

    // MFMA phase
    const int quad = lane >> 4, nl = lane & 15;
    const int rowA = wave * 16 + nl;
    v4f acc2[NT];
#pragma unroll
    for (int i = 0; i < NT; ++i) acc2[i] = (v4f){0.f, 0.f, 0.f, 0.f};
#pragma unroll
    for (int ks = 0; ks < KS; ++ks) {
        v8h a = *(const v8h*)(Xh + rowA * KP + ks * 32 + quad * 8);
#pragma unroll
        for (int ntl = 0; ntl < NT; ++ntl) {
            v8h b = *(const v8h*)(Wz + ((ntl * KS + ks) * 64 + lane) * 8);
            acc2[ntl] = __builtin_amdgcn_mfma_f32_16x16x32_f16(a, b, acc2[ntl], 0, 0, 0);
        }
    }
#pragma unroll
    for (int r = 0; r < 4; ++r) {
        int gr = row0 + wave * 16 + quad * 4 + r;
        if (gr < Nloc) {
            float dv = dinv_g[gr];
#pragma unroll
            for (int ntl = 0; ntl < NT; ++ntl)
                Hout[(size_t)gr * M + ntl * 16 + nl] = __float2half(acc2[ntl][r] * dv);
        }
    }
}

// ---- standalone aggregate (final layer) ----
template <int M>
__device__ void agg_body(int bid, const __half* __restrict__ H,
                         const int* __restrict__ off_g, const int* __restrict__ csr,
                         const float* __restrict__ dinv_g, const float* __restrict__ b,
                         __half* __restrict__ out, int Nloc) {
    constexpr int L = M / 4, NPW = 64 / L;
    int lane = threadIdx.x & 63;
    int wave = threadIdx.x >> 6;
    int fq   = lane & (L - 1);
    int sub  = lane / L;
    int node = (bid * 4 + wave) * NPW + sub;
    if (node >= Nloc) return;
    const float2* H4 = (const float2*)H;
    int j0 = off_g[node], j1 = off_g[node + 1];
    float4 acc = load4h(H4, (size_t)node * L + fq);  // self-loop
    gather_acc(H4, L, fq, csr, j0, j1, acc);
    float  dv = dinv_g[node];
    float4 bb = ((const float4*)b)[fq];
    float  vx = dv * acc.x + bb.x;
    float  vy = dv * acc.y + bb.y;
    float  vz = dv * acc.z + bb.z;
    float  vw = dv * acc.w + bb.w;
    union { float2 f2; __half2 h2[2]; } o;
    o.h2[0] = __floats2half2_rn(vx > 0.f ? vx : 0.f, vy > 0.f ? vy : 0.f);
    o.h2[1] = __floats2half2_rn(vz > 0.f ? vz : 0.f, vw > 0.f ? vw : 0.f);
    ((float2*)out)[(size_t)node * L + fq] = o.f2;
}

// ---- fused two-side kernels ----
__global__ __launch_bounds__(256) void gemmBoth0(const float* __restrict__ Xc, const float* __restrict__ Wc,
                                                 __half* __restrict__ cH, int Nc,
                                                 const float* __restrict__ Xs, const float* __restrict__ Ws,
                                                 __half* __restrict__ sH, int Ns,
                                                 const float* __restrict__ dinv_all, int Nc_pad, int nbC) {
    __shared__ __align__(16) char smem[17408];
    if (blockIdx.x < nbC) gemm_mfma<64, 64, float>(blockIdx.x, Xc, Wc, dinv_all, cH, Nc, smem);
    else                  gemm_mfma<64, 32, float>(blockIdx.x - nbC, Xs, Ws, dinv_all + Nc_pad, sH, Ns, smem);
}

__global__ __launch_bounds__(256) void aggGemmBoth(const __half* __restrict__ cHin, __half* __restrict__ cHout,
                                                   const __half* __restrict__ sHin, __half* __restrict__ sHout,
                                                   const int* __restrict__ off_all, const int* __restrict__ csr_all,
                                                   const float* __restrict__ dinv_all,
                                                   const float* __restrict__ bc, const float* __restrict__ bs,
                                                   const float* __restrict__ Wc, const float* __restrict__ Ws,
                                                   int Nc, int Ns, int Nc_pad, int nbC) {
    __shared__ __align__(16) char smem[17408];
    if (blockIdx.x < nbC)
        aggGemm_body<64>(blockIdx.x, cHin, off_all, csr_all, dinv_all, bc, Wc, cHout, Nc, smem);
    else
        aggGemm_body<32>(blockIdx.x - nbC, sHin, off_all + Nc_pad, csr_all,
                         dinv_all + Nc_pad, bs, Ws, sHout, Ns, smem);
}

__global__ __launch_bounds__(256) void aggBoth(const __half* __restrict__ cH, const __half* __restrict__ sH,
                                               const int* __restrict__ off_all, const int* __restrict__ csr_all,
                                               const float* __restrict__ dinv_all,
                                               const float* __restrict__ bc, const float* __restrict__ bs,
                                               __half* __restrict__ outc, __half* __restrict__ outs,
                                               int Nc, int Ns, int Nc_pad, int nbC) {
    if (blockIdx.x < nbC)
        agg_body<64>(blockIdx.x, cH, off_all, csr_all, dinv_all, bc, outc, Nc);
    else
        agg_body<32>(blockIdx.x - nbC, sH, off_all + Nc_pad, csr_all,
                     dinv_all + Nc_pad, bs, outs, Ns);
}

// ---- fused pooling + MLP head ----
__device__ __forceinline__ int lbound(const int* __restrict__ a, int n, int key) {
    int lo = 0, hi = n;
    while (lo < hi) {
        int mid = (lo + hi) >> 1;
        if (a[mid] < key) lo = mid + 1; else hi = mid;
    }
    return lo;
}

__global__ __launch_bounds__(128) void poolDense(const __half* __restrict__ cX, const int* __restrict__ c_batch, int Nc,
                                                 const __half* __restrict__ sX, const int* __restrict__ s_batch, int Ns,
                                                 const float* __restrict__ Wd, const float* __restrict__ bd,
                                                 const float* __restrict__ Wo, const float* __restrict__ bo,
                                                 float* __restrict__ outv, float* __restrict__ embed) {
    __shared__ float e[192];
    __shared__ float red[128];
    int g = blockIdx.x, t = threadIdx.x;
    if (t < 64) {
        int lo = lbound(c_batch, Nc, g), hi = lbound(c_batch, Nc, g + 1);
        float mx = 0.f, sm = 0.f;
        for (int i = lo; i < hi; ++i) {
            float v = __half2float(cX[(size_t)i * 64 + t]);
            mx = fmaxf(mx, v); sm += v;
        }
        int cn = hi - lo;
        e[t]      = mx;
        e[64 + t] = sm / (float)(cn > 0 ? cn : 1);
    } else if (t < 96) {
        int f  = t - 64;
        int lo = lbound(s_batch, Ns, g), hi = lbound(s_batch, Ns, g + 1);
        float mx = 0.f, sm = 0.f;
        for (int i = lo; i < hi; ++i) {
            float v = __half2float(sX[(size_t)i * 32 + f]);
            mx = fmaxf(mx, v); sm += v;
        }
        int cn = hi - lo;
        e[128 + f] = mx;
        e[160 + f] = sm / (float)(cn > 0 ? cn : 1);
    }
    __syncthreads();
    for (int k = t; k < 192; k += 128) embed[(size_t)g * 192 + k] = e[k];
    float acc = bd[t];
    for (int k = 0; k < 192; ++k) acc += e[k] * Wd[k * 128 + t];
    float d = acc > 0.f ? acc : 0.f;
    red[t]  = d * Wo[t];
    __syncthreads();
    for (int ofs = 64; ofs > 0; ofs >>= 1) {
        if (t < ofs) red[t] += red[t + ofs];
        __syncthreads();
    }
    if (t == 0) outv[g] = red[0] + bo[0];
}

// ---------------------------------------------------------------------------

extern "C" void kernel_launch(void* const* d_in, const int* in_sizes, int n_in,
                              void* d_out, int out_size, void* d_ws, size_t ws_size,
                              hipStream_t stream) {
    const float* c       = (const float*)d_in[0];
    const int*   c_edge  = (const int*)d_in[1];
    const int*   c_batch = (const int*)d_in[2];
    const float* s       = (const float*)d_in[3];
    const int*   s_edge  = (const int*)d_in[4];
    const int*   s_batch = (const int*)d_in[5];
    const float* Wc0 = (const float*)d_in[6],  *bc0 = (const float*)d_in[7];
    const float* Wc1 = (const float*)d_in[8],  *bc1 = (const float*)d_in[9];
    const float* Wc2 = (const float*)d_in[10], *bc2 = (const float*)d_in[11];
    const float* Ws0 = (const float*)d_in[12], *bs0 = (const float*)d_in[13];
    const float* Ws1 = (const float*)d_in[14], *bs1 = (const float*)d_in[15];
    const float* Ws2 = (const float*)d_in[16], *bs2 = (const float*)d_in[17];
    const float* Wd  = (const float*)d_in[18], *bd  = (const float*)d_in[19];
    const float* Wo  = (const float*)d_in[20], *bo  = (const float*)d_in[21];

    const int Nc = in_sizes[0] / 64;
    const int Ec = in_sizes[1] / 2;
    const int Ns = in_sizes[3] / 64;
    const int Es = in_sizes[4] / 2;
    const int G  = out_size / 193;  // 2048
    const int Nc_pad   = cdiv(Nc, 512) * 512;
    const int Ns_pad   = cdiv(Ns, 512) * 512;
    const int Ntot_pad = Nc_pad + Ns_pad;
    const int Etot     = Ec + Es;
    const int nbuck    = Ntot_pad >> 9;

    // ---- workspace carve ----
    char* p = (char*)d_ws;
    auto  alloc = [&](size_t bytes) -> void* {
        void* r = (void*)p;
        p += (bytes + 255) & ~(size_t)255;
        return r;
    };
    int*      bucket_fill = (int*)alloc(512 * 4);
    int*      bucket_base = (int*)alloc(512 * 4);
    unsigned* pk          = (unsigned*)alloc((size_t)nbuck * BUCKET_CAP * 4);
    int*      off_all     = (int*)alloc(((size_t)Ntot_pad + 1) * 4);
    int*      csr_all     = (int*)alloc((size_t)Etot * 4);
    float*    dinv_all    = (float*)alloc((size_t)Ntot_pad * 4);
    __half*   bufC        = (__half*)alloc((size_t)Nc * 64 * 2);   // final layer out (pool input)
    __half*   bufS        = (__half*)alloc((size_t)Ns * 32 * 2);
    __half*   cHa         = (__half*)alloc((size_t)Nc * 64 * 2);   // H ping
    __half*   sHa         = (__half*)alloc((size_t)Ns * 32 * 2);
    __half*   cHb         = (__half*)alloc((size_t)Nc * 64 * 2);   // H pong
    __half*   sHb         = (__half*)alloc((size_t)Ns * 32 * 2);

    float* outv  = (float*)d_out;  // [G]
    float* embed = outv + G;       // [G][192]

    const int nbGmC = cdiv(Nc, 64), nbGmS = cdiv(Ns, 64);
    const int nbFzC = Nc_pad / 64,  nbFzS = Ns_pad / 64;   // fused agg+gemm blocks
    const int nbAgC = Nc_pad / 16,  nbAgS = Ns_pad / 32;   // final agg blocks

    // 1) CSR build (bucketed, LDS atomics only)
    zero_int<<<cdiv(nbuck, 256), 256, 0, stream>>>(bucket_fill, nbuck);
    p1_partition<<<cdiv(Etot, P1_CHUNK), 256, 0, stream>>>(c_edge, Ec, s_edge, Es,
                                                           Nc_pad, Etot, nbuck, bucket_fill, pk);
    p2_scanbuckets<<<1, 512, 0, stream>>>(bucket_fill, nbuck, bucket_base, off_all, Ntot_pad, Etot);
    p3_build<<<nbuck, 512, 0, stream>>>(pk, bucket_fill, bucket_base,
                                        off_all, dinv_all, csr_all);

    // 2) layer-0 GEMM (fp32 inputs)
    gemmBoth0<<<nbGmC + nbGmS, 256, 0, stream>>>(c, Wc0, cHa, Nc, s, Ws0, sHa, Ns,
                                                 dinv_all, Nc_pad, nbGmC);
    // 3) fused: layer-0 aggregate + layer-1 GEMM
    aggGemmBoth<<<nbFzC + nbFzS, 256, 0, stream>>>(cHa, cHb, sHa, sHb,
                                                   off_all, csr_all, dinv_all,
                                                   bc0, bs0, Wc1, Ws1, Nc, Ns, Nc_pad, nbFzC);
    // 4) fused: layer-1 aggregate + layer-2 GEMM
    aggGemmBoth<<<nbFzC + nbFzS, 256, 0, stream>>>(cHb, cHa, sHb, sHa,
                                                   off_all, csr_all, dinv_all,
                                                   bc1, bs1, Wc2, Ws2, Nc, Ns, Nc_pad, nbFzC);
    // 5) final aggregate -> pool input
    aggBoth<<<nbAgC + nbAgS, 256, 0, stream>>>(cHa, sHa, off_all, csr_all, dinv_all,
                                               bc2, bs2, bufC, bufS, Nc, Ns, Nc_pad, nbAgC);

    // 6) fused pooling + MLP
    poolDense<<<G, 128, 0, stream>>>(bufC, c_batch, Nc, bufS, s_batch, Ns,
                                     Wd, bd, Wo, bo, outv, embed);
}